// Round 6
// baseline (131084.253 us; speedup 1.0000x reference)
//
#include <hip/hip_runtime.h>
#include <hip/hip_fp16.h>

#define TT 1024
#define BB 64
#define HH 256
#define NTH 1024

#define L2E 1.44269504089f   // log2(e)
#define PM  2.88539008178f   // 2*log2(e): tanh(x) = 1 - 2/(1+2^(PM*x))

// ws: fp16 uam history, premultiplied by PM, transposed [b][h][t2]
#define UAM_BYTES (1ull * BB * HH * TT * 2)   // 33.55 MB
#define WS_NEED   UAM_BYTES

#if __has_builtin(__builtin_amdgcn_exp2f)
#define EXP2F(x) __builtin_amdgcn_exp2f(x)
#else
#define EXP2F(x) exp2f(x)
#endif

__device__ __forceinline__ float tanh_fast(float xx) {
  float e = EXP2F(PM * xx);
  return 1.0f - 2.0f * __builtin_amdgcn_rcpf(e + 1.0f);
}

extern "C" __global__ void __launch_bounds__(NTH, 1)
memrnn_scan(const float* __restrict__ x, const float* __restrict__ U_w,
            const float* __restrict__ U_b, const float* __restrict__ V_w,
            const float* __restrict__ Ua_w, const float* __restrict__ Va_w,
            const float* __restrict__ vvec, float* __restrict__ out,
            __half* __restrict__ uamh)
{
  const int b    = blockIdx.x;      // one block per batch element
  const int tid  = threadIdx.x;
  const int lane = tid & 63;
  const int wav  = tid >> 6;
  const int r4   = tid >> 2;        // gemv row 0..255 (4 threads/row)
  const int c4   = tid & 3;         // col-chunk: cols c4*64 .. c4*64+63

  __half* ua_b = uamh + (size_t)b * HH * TT;   // block-private history [h][t2]

  __shared__ float2 s_av[HH];     // .x = PM*(Va*st)[h], .y = v[h]
  __shared__ float  s_e[TT];      // w(t2) = exp(e(t2))
  __shared__ float  s_x[HH];      // x[t][b][:]
  __shared__ float  s_st[HH];     // carried st (pre-tanh)
  __shared__ float  s_h[HH];      // h[t-1] (= mem[t-1])
  __shared__ float  s_bias[HH];
  __shared__ float  s_num[4 * HH];
  __shared__ float  s_den[4];

  // ---------------- prologue (t = 0) ----------------
  if (tid < HH) {
    s_x[tid]    = x[(size_t)b * HH + tid];
    s_av[tid]   = make_float2(0.f, vvec[tid]);
    s_bias[tid] = U_b[tid];
  }
  __syncthreads();
  float Vs = 0.f;                      // sum of v (for e = Vs - 2*sum(v*rcp))
#pragma unroll 8
  for (int k = 0; k < HH; ++k) Vs += s_av[k].y;
  {
    const float* rowU = U_w + r4 * HH + c4 * 64;
    float acc = 0.f;
#pragma unroll
    for (int k = 0; k < 16; ++k) {
      const float4 wu = *(const float4*)(rowU + k * 4);
      const int i = c4 * 64 + k * 4;
      acc += wu.x * s_x[i] + wu.y * s_x[i + 1] + wu.z * s_x[i + 2] + wu.w * s_x[i + 3];
    }
    acc += __shfl_xor(acc, 1); acc += __shfl_xor(acc, 2);
    if (c4 == 0) {
      const float st0 = acc + s_bias[r4];        // pre-tanh state at t=0
      const float h0  = tanh_fast(st0);          // V(hidden)=0 at t=0
      s_st[r4] = st0;
      s_h[r4]  = h0;
      out[(size_t)b * HH + r4] = h0;             // mem[0]
    }
  }
  __syncthreads();
  {
    const float* rowA = Ua_w + r4 * HH + c4 * 64;
    float acc = 0.f;
#pragma unroll
    for (int k = 0; k < 16; ++k) {
      const float4 wa = *(const float4*)(rowA + k * 4);
      const int i = c4 * 64 + k * 4;
      acc += wa.x * s_h[i] + wa.y * s_h[i + 1] + wa.z * s_h[i + 2] + wa.w * s_h[i + 3];
    }
    acc += __shfl_xor(acc, 1); acc += __shfl_xor(acc, 2);
    if (c4 == 0) ua_b[(size_t)r4 * TT + 0] = __float2half(PM * acc);  // uam[0], premult
  }

  // ---------------- main loop ----------------
  for (int t = 1; t < TT; ++t) {
    // -- A: stage x[t]; a = PM*(Va*st) --
    if (tid < HH) s_x[tid] = x[((size_t)t * BB + b) * HH + tid];
    {
      const float* rowVa = Va_w + r4 * HH + c4 * 64;
      float acc = 0.f;
#pragma unroll
      for (int k = 0; k < 16; ++k) {
        const float4 wv = *(const float4*)(rowVa + k * 4);
        const int i = c4 * 64 + k * 4;
        acc += wv.x * s_st[i] + wv.y * s_st[i + 1] + wv.z * s_st[i + 2] + wv.w * s_st[i + 3];
      }
      acc += __shfl_xor(acc, 1); acc += __shfl_xor(acc, 2);
      if (c4 == 0) s_av[r4].x = PM * acc;
    }
    __syncthreads();   // also makes last step's uam[:,t-1] stores visible (vmcnt drained)

    // -- B: e-pass. lane-per-t2 (single chunk: 1024 lanes >= t), serial h --
    {
      const int t2 = wav * 64 + lane;   // == tid
      if (t2 < t) {
        const __half* up = ua_b + t2;   // + h*TT
        float p2 = 0.f;
#pragma unroll 8
        for (int h = 0; h < HH; ++h) {
          const float2 av = s_av[h];    // uniform broadcast
          const float  uu = __half2float(up[(size_t)h * TT]);
          p2 = fmaf(av.y, __builtin_amdgcn_rcpf(1.f + EXP2F(av.x + uu)), p2);
        }
        s_e[t2] = EXP2F(L2E * (Vs - 2.f * p2));  // w = exp(e); |e| <= ~13, no max pass
      }
    }
    __syncthreads();

    // -- C: num/den over 4 t2-stripes; mem read directly from out --
    {
      const int s4 = tid >> 8, h = tid & 255;
      float num = 0.f, den = 0.f;
      const float* op = out + (size_t)b * HH + h;
#pragma unroll 4
      for (int t2 = s4; t2 < t; t2 += 4) {
        const float w = s_e[t2];
        den += w;
        num = fmaf(w, op[(size_t)t2 * (BB * HH)], num);
      }
      s_num[s4 * HH + h] = num;
      if (h == 0) s_den[s4] = den;
    }
    __syncthreads();

    // -- D: ct; st_new = h[t-1] + ct --
    if (tid < HH) {
      const float nm = s_num[tid] + s_num[HH + tid] + s_num[2 * HH + tid] + s_num[3 * HH + tid];
      const float dn = s_den[0] + s_den[1] + s_den[2] + s_den[3];
      s_st[tid] = s_h[tid] + nm * __builtin_amdgcn_rcpf(dn);
    }
    __syncthreads();

    // -- E: h = tanh(V*st_new + U*x + bias) --
    {
      const float* rowV = V_w + r4 * HH + c4 * 64;
      const float* rowU = U_w + r4 * HH + c4 * 64;
      float acc = 0.f;
#pragma unroll
      for (int k = 0; k < 16; ++k) {
        const float4 wv = *(const float4*)(rowV + k * 4);
        const float4 wu = *(const float4*)(rowU + k * 4);
        const int i = c4 * 64 + k * 4;
        acc += wv.x * s_st[i] + wv.y * s_st[i + 1] + wv.z * s_st[i + 2] + wv.w * s_st[i + 3]
             + wu.x * s_x[i]  + wu.y * s_x[i + 1]  + wu.z * s_x[i + 2]  + wu.w * s_x[i + 3];
      }
      acc += __shfl_xor(acc, 1); acc += __shfl_xor(acc, 2);
      if (c4 == 0) {
        const float hv = tanh_fast(acc + s_bias[r4]);
        out[((size_t)t * BB + b) * HH + r4] = hv;   // mem[t]
        s_h[r4] = hv;
      }
    }
    __syncthreads();

    // -- F: uam[:,t] = PM*(Ua*h) -> private history (read next step after A's sync) --
    if (t < TT - 1) {
      const float* rowA = Ua_w + r4 * HH + c4 * 64;
      float acc = 0.f;
#pragma unroll
      for (int k = 0; k < 16; ++k) {
        const float4 wa = *(const float4*)(rowA + k * 4);
        const int i = c4 * 64 + k * 4;
        acc += wa.x * s_h[i] + wa.y * s_h[i + 1] + wa.z * s_h[i + 2] + wa.w * s_h[i + 3];
      }
      acc += __shfl_xor(acc, 1); acc += __shfl_xor(acc, 2);
      if (c4 == 0) ua_b[(size_t)r4 * TT + t] = __float2half(PM * acc);
    }
    // no sync needed here: next A writes s_x/s_av.x (readers all passed E's sync),
    // and A's sync orders F's global stores before B's loads.
  }
}

__global__ void ws_sentinel(float* out) { out[0] = 2.0e6f; }

extern "C" void kernel_launch(void* const* d_in, const int* in_sizes, int n_in,
                              void* d_out, int out_size, void* d_ws, size_t ws_size,
                              hipStream_t stream) {
  const float* x    = (const float*)d_in[0];
  const float* U_w  = (const float*)d_in[1];
  const float* U_b  = (const float*)d_in[2];
  const float* V_w  = (const float*)d_in[3];
  const float* Ua_w = (const float*)d_in[4];
  const float* Va_w = (const float*)d_in[5];
  const float* v    = (const float*)d_in[6];
  float* out = (float*)d_out;

  if (ws_size < WS_NEED) {            // diagnosable failure signature (absmax ~2e6)
    ws_sentinel<<<1, 1, 0, stream>>>(out);
    return;
  }
  memrnn_scan<<<dim3(BB), dim3(NTH), 0, stream>>>(
      x, U_w, U_b, V_w, Ua_w, Va_w, v, out, (__half*)d_ws);
}

// Round 9
// 81936.084 us; speedup vs baseline: 1.5998x; 1.5998x over previous
//
#include <hip/hip_runtime.h>
#include <hip/hip_fp16.h>

#define TT 1024
#define BB 64
#define HH 256
#define NTH 512
#define RMAX 256            // TT/4 history rows per slice

#define L2E 1.44269504089f
#define PM  2.88539008178f  // 2*log2(e): tanh(x) = 1 - 2/(1+2^(PM*x))

// ---- ws layout ----
#define MEM16_BYTES (256ull * RMAX * HH * 2)      // [blk][row][h] fp16, block-private (33.55MB)
#define NP_OFF      (MEM16_BYTES)
#define NP_STRIDE   264                           // floats per record: 256 num + den
#define NP_BYTES    (1ull * BB * 4 * 2 * NP_STRIDE * 4)   // [b][s][parity]
#define FL_OFF      (NP_OFF + NP_BYTES)
#define FL_BYTES    (1ull * BB * 4 * 32 * 4)
#define BR_OFF      (FL_OFF + FL_BYTES)
#define WS_NEED     (BR_OFF + 128)                // ~34.6 MB

#if __has_builtin(__builtin_amdgcn_exp2f)
#define EXP2F(x) __builtin_amdgcn_exp2f(x)
#else
#define EXP2F(x) exp2f(x)
#endif
#define RCPF(x) __builtin_amdgcn_rcpf(x)

__device__ __forceinline__ float tanh_pm(float xx) {
  return 1.0f - 2.0f * RCPF(1.0f + EXP2F(PM * xx));
}

#define AGT __HIP_MEMORY_SCOPE_AGENT
__device__ __forceinline__ float ld_cg(const float* p) {
  return __hip_atomic_load(p, __ATOMIC_RELAXED, AGT);
}
__device__ __forceinline__ void st_cg(float* p, float v) {
  __hip_atomic_store(p, v, __ATOMIC_RELAXED, AGT);
}

// r3-proven rendezvous: drain stores (barrier => vmcnt0) then RELEASE RMW.
__device__ __forceinline__ void post1(int* slot) {
  __syncthreads();
  if (threadIdx.x == 0)
    __hip_atomic_fetch_add(slot, 1, __ATOMIC_RELEASE, AGT);
}
__device__ __forceinline__ void wait4(int* base, int val, int* broken) {
  if (threadIdx.x < 4) {
    const int* f = base + threadIdx.x * 32;
    long it = 0;
    while (__hip_atomic_load(f, __ATOMIC_RELAXED, AGT) < val) {
      if (__hip_atomic_load(broken, __ATOMIC_RELAXED, AGT)) break;
      if (++it > 20000000) {
        __hip_atomic_store(broken, 1, __ATOMIC_RELAXED, AGT);
        break;
      }
    }
  }
  __syncthreads();
}

// fp16-packed persistent gemv: 64 half2 = 128 columns per thread (full coverage
// with 2 threads/row).  r7/r8 BUG: f32 wX[64] covered only cols [cp*128, +64).
#define GEMV128(accum, W, SRC)                                        \
  _Pragma("unroll")                                                   \
  for (int k = 0; k < 64; ++k) {                                      \
    const float2 w2 = __half22float2(W[k]);                           \
    accum = fmaf(w2.x, SRC[cp * 128 + 2 * k], accum);                 \
    accum = fmaf(w2.y, SRC[cp * 128 + 2 * k + 1], accum);             \
  }

extern "C" __global__ void __launch_bounds__(NTH, 2)
memrnn_scan(const float* __restrict__ x, const float* __restrict__ U_w,
            const float* __restrict__ U_b, const float* __restrict__ V_w,
            const float* __restrict__ Ua_w, const float* __restrict__ Va_w,
            const float* __restrict__ vvec, float* __restrict__ out,
            char* __restrict__ wsb)
{
  const int blk = blockIdx.x;
  const int b   = blk & 63;       // batch element
  const int s   = blk >> 6;       // time-slice: owns t2 == s (mod 4)
  const int tid = threadIdx.x;
  const int rr  = tid >> 1;       // gemv row 0..255 (2 threads/row)
  const int cp  = tid & 1;        // col half (128 cols each)
  const int sid = tid >> 6;       // num-pass stripe 0..7
  const int qq  = tid & 63;       // num-pass h-quad 0..63

  __half* mem16 = (__half*)wsb + (size_t)blk * RMAX * HH;   // private fp16 h rows (own t2)
  float*  npart = (float*)(wsb + NP_OFF);
  int* flags  = (int*)(wsb + FL_OFF) + b * 4 * 32;
  int* broken = (int*)(wsb + BR_OFF);

  // ---- full-H weights in registers: 3 x 64 half2 (128 f32 cols each) ----
  __half2 wV[64], wVa[64], wUa[64];
#pragma unroll
  for (int k = 0; k < 64; ++k) {
    const int off = rr * HH + cp * 128 + 2 * k;
    wV [k] = __float22half2_rn(*(const float2*)(V_w  + off));
    wVa[k] = __float22half2_rn(*(const float2*)(Va_w + off));
    wUa[k] = __float22half2_rn(*(const float2*)(Ua_w + off));
  }

  __shared__ __half s_uam[RMAX * HH];   // 128KB: PM*uam rows (own t2), XOR-swizzled
  __shared__ float  s_v[HH], s_a[HH], s_x2[HH], s_st[HH], s_h[HH], s_bias[HH];
  __shared__ float  s_w[RMAX];          // softmax weights for own t2
  __shared__ float  s_np[8][HH];
  __shared__ float  s_npd[8];

  // ================= prologue (t = 0) =================
  if (tid < HH) {
    s_x2[tid]   = x[(size_t)b * HH + tid];
    s_v[tid]    = vvec[tid];
    s_bias[tid] = U_b[tid];
  }
  __syncthreads();
  float Vs = 0.f;
#pragma unroll 8
  for (int k = 0; k < HH; ++k) Vs += s_v[k];
  {
    float u0 = 0.f;
    const float* Up = U_w + rr * HH + cp * 128;
#pragma unroll
    for (int k4 = 0; k4 < 32; ++k4) {
      const float4 u4 = *(const float4*)(Up + k4 * 4);
      const int i = cp * 128 + k4 * 4;
      u0 = fmaf(u4.x, s_x2[i], u0);   u0 = fmaf(u4.y, s_x2[i+1], u0);
      u0 = fmaf(u4.z, s_x2[i+2], u0); u0 = fmaf(u4.w, s_x2[i+3], u0);
    }
    u0 += __shfl_xor(u0, 1);
    if (cp == 0) {
      const float st0 = u0 + s_bias[rr];
      s_st[rr] = st0;
      s_h[rr]  = tanh_pm(st0);        // V(hidden)=0 at t=0
    }
  }
  __syncthreads();
  if (s == 0) {                        // owner of t2=0
    float au = 0.f;
    GEMV128(au, wUa, s_h);
    au += __shfl_xor(au, 1);
    if (cp == 0)
      *(__half*)((char*)s_uam + ((rr * 2) ^ 0)) = __float2half(PM * au);  // row0 swz=0
    if (tid < HH) {
      mem16[tid] = __float2half(s_h[tid]);
      out[(size_t)b * HH + tid] = s_h[tid];
    }
  }
  if (tid < HH) s_x2[tid] = x[((size_t)BB + b) * HH + tid];   // x[1]
  __syncthreads();
  float ux_cur = 0.f;                  // U.x[1] partial (own half)
  {
    const float* Up = U_w + rr * HH + cp * 128;
#pragma unroll
    for (int k4 = 0; k4 < 32; ++k4) {
      const float4 u4 = *(const float4*)(Up + k4 * 4);
      const int i = cp * 128 + k4 * 4;
      ux_cur = fmaf(u4.x, s_x2[i], ux_cur);   ux_cur = fmaf(u4.y, s_x2[i+1], ux_cur);
      ux_cur = fmaf(u4.z, s_x2[i+2], ux_cur); ux_cur = fmaf(u4.w, s_x2[i+3], ux_cur);
    }
  }

  // ================= main loop =================
  for (int t = 1; t < TT; ++t) {
    __syncthreads();                   // prev-step I writes (LDS/global) visible
    const int cnt = (t - s + 3) >> 2;  // own t2 rows with t2 < t
    const int par = t & 1;             // npart parity buffer

    // -- A: stage x[t+1]; a = PM*(Va*st) (redundant full gemv) --
    if (t < TT - 1 && tid < HH) s_x2[tid] = x[((size_t)(t + 1) * BB + b) * HH + tid];
    {
      float aa = 0.f;
      GEMV128(aa, wVa, s_st);
      aa += __shfl_xor(aa, 1);
      if (cp == 0) s_a[rr] = PM * aa;
    }
    __syncthreads();

    // -- B: e for own t2 (LDS-only, one pair of threads per row) --
    if (rr < cnt) {
      float p2 = 0.f;
#pragma unroll
      for (int m = 0; m < 16; ++m) {
        const uint4 raw = *(const uint4*)((const char*)s_uam + rr * 512 +
                                          (((cp << 8) | (m << 4)) ^ ((rr & 7) << 4)));
        const __half2* hp = (const __half2*)&raw;
#pragma unroll
        for (int e = 0; e < 4; ++e) {
          const float2 f = __half22float2(hp[e]);
          const int h = cp * 128 + m * 8 + e * 2;
          p2 = fmaf(s_v[h],     RCPF(1.f + EXP2F(s_a[h]     + f.x)), p2);
          p2 = fmaf(s_v[h + 1], RCPF(1.f + EXP2F(s_a[h + 1] + f.y)), p2);
        }
      }
      p2 += __shfl_xor(p2, 1);
      if (cp == 0) s_w[rr] = EXP2F(L2E * (Vs - 2.f * p2));   // exp(e), |e|<=~13
    }
    __syncthreads();

    // -- C: partial num/den over own rows (mem16 private, coalesced 8B loads) --
    {
      float n0 = 0.f, n1 = 0.f, n2 = 0.f, n3 = 0.f, dd = 0.f;
      for (int g = sid; g < cnt; g += 8) {
        const float w = s_w[g];
        const uint2 rawm = *(const uint2*)(mem16 + (size_t)g * HH + qq * 4);
        const float2 f0 = __half22float2(*(const __half2*)&rawm.x);
        const float2 f1 = __half22float2(*(const __half2*)&rawm.y);
        n0 = fmaf(w, f0.x, n0); n1 = fmaf(w, f0.y, n1);
        n2 = fmaf(w, f1.x, n2); n3 = fmaf(w, f1.y, n3);
        dd += w;
      }
      s_np[sid][qq * 4 + 0] = n0; s_np[sid][qq * 4 + 1] = n1;
      s_np[sid][qq * 4 + 2] = n2; s_np[sid][qq * 4 + 3] = n3;
      if (qq == 0) s_npd[sid] = dd;
    }
    __syncthreads();

    // -- D: publish record into parity buffer; post flag --
    {
      float* rec = npart + (((size_t)b * 4 + s) * 2 + par) * NP_STRIDE;
      if (tid < HH) {
        float nm = 0.f;
#pragma unroll
        for (int i = 0; i < 8; ++i) nm += s_np[i][tid];
        st_cg(rec + tid, nm);
      } else if (tid == HH) {
        float dn = 0.f;
#pragma unroll
        for (int i = 0; i < 8; ++i) dn += s_npd[i];
        st_cg(rec + 256, dn);
      }
    }
    post1(flags + s * 32);

    // -- E: overlap the wait with U.x[t+1] gemv (L2 stream) --
    float uxn = 0.f;
    if (t < TT - 1) {
      const float* Up = U_w + rr * HH + cp * 128;
#pragma unroll
      for (int k4 = 0; k4 < 32; ++k4) {
        const float4 u4 = *(const float4*)(Up + k4 * 4);
        const int i = cp * 128 + k4 * 4;
        uxn = fmaf(u4.x, s_x2[i], uxn);     uxn = fmaf(u4.y, s_x2[i + 1], uxn);
        uxn = fmaf(u4.z, s_x2[i + 2], uxn); uxn = fmaf(u4.w, s_x2[i + 3], uxn);
      }
    }

    // -- F: single rendezvous --
    wait4(flags, t, broken);

    // -- G: combine (parity buffer) -> ct -> st_new (redundant, identical) --
    if (tid < HH) {
      const float* np0 = npart + ((size_t)b * 8 + par) * NP_STRIDE;
      const float nm = ld_cg(np0 + tid) + ld_cg(np0 + 2 * NP_STRIDE + tid) +
                       ld_cg(np0 + 4 * NP_STRIDE + tid) + ld_cg(np0 + 6 * NP_STRIDE + tid);
      const float dn = ld_cg(np0 + 256) + ld_cg(np0 + 2 * NP_STRIDE + 256) +
                       ld_cg(np0 + 4 * NP_STRIDE + 256) + ld_cg(np0 + 6 * NP_STRIDE + 256);
      s_st[tid] = s_h[tid] + nm * RCPF(dn);       // last_h + ct
    }
    __syncthreads();

    // -- H: h = tanh(V*st_new + Ux[t] + bias) (redundant full gemv) --
    {
      float ah = ux_cur;
      GEMV128(ah, wV, s_st);
      ah += __shfl_xor(ah, 1);
      if (cp == 0) s_h[rr] = tanh_pm(ah + s_bias[rr]);
    }
    __syncthreads();

    // -- I: owner of t2=t stores uam row (LDS), mem16 row, out row --
    if (s == (t & 3)) {
      float au = 0.f;
      GEMV128(au, wUa, s_h);
      au += __shfl_xor(au, 1);
      const int row = t >> 2;
      if (cp == 0)
        *(__half*)((char*)s_uam + row * 512 + ((rr * 2) ^ ((row & 7) << 4))) =
            __float2half(PM * au);
      if (tid < HH) {
        mem16[(size_t)row * HH + tid] = __float2half(s_h[tid]);
        out[((size_t)t * BB + b) * HH + tid] = s_h[tid];
      }
    }
    ux_cur = uxn;
  }

  if (tid == 0 && __hip_atomic_load(broken, __ATOMIC_RELAXED, AGT))
    st_cg(&out[0], 1.0e6f);   // deadlock signature
}

__global__ void ws_sentinel(float* out) { out[0] = 2.0e6f; }

extern "C" void kernel_launch(void* const* d_in, const int* in_sizes, int n_in,
                              void* d_out, int out_size, void* d_ws, size_t ws_size,
                              hipStream_t stream) {
  const float* x    = (const float*)d_in[0];
  const float* U_w  = (const float*)d_in[1];
  const float* U_b  = (const float*)d_in[2];
  const float* V_w  = (const float*)d_in[3];
  const float* Ua_w = (const float*)d_in[4];
  const float* Va_w = (const float*)d_in[5];
  const float* v    = (const float*)d_in[6];
  float* out = (float*)d_out;

  if (ws_size < WS_NEED) {            // diagnosable failure signature (absmax ~2e6)
    ws_sentinel<<<1, 1, 0, stream>>>(out);
    return;
  }
  hipMemsetAsync((char*)d_ws + FL_OFF, 0, (size_t)(WS_NEED - FL_OFF), stream);
  memrnn_scan<<<dim3(BB * 4), dim3(NTH), 0, stream>>>(
      x, U_w, U_b, V_w, Ua_w, Va_w, v, out, (char*)d_ws);
}

// Round 10
// 70143.799 us; speedup vs baseline: 1.8688x; 1.1681x over previous
//
#include <hip/hip_runtime.h>
#include <hip/hip_fp16.h>

#define TT 1024
#define BB 64
#define HH 256
#define NTH 512
#define RMAX 256            // TT/4 history rows per slice

#define L2E 1.44269504089f
#define PM  2.88539008178f  // 2*log2(e): tanh(x) = 1 - 2/(1+2^(PM*x))

// ---- ws layout ----
#define MEM16_BYTES (256ull * RMAX * HH * 2)      // [blk][row][h] fp16, block-private (33.55MB)
#define NP_OFF      (MEM16_BYTES)
#define NP_STRIDE   264                           // floats per record: 256 num + den
#define NP_BYTES    (1ull * BB * 4 * 2 * NP_STRIDE * 4)   // [b][s][parity]
#define FL_OFF      (NP_OFF + NP_BYTES)
#define FL_BYTES    (1ull * BB * 4 * 32 * 4)
#define BR_OFF      (FL_OFF + FL_BYTES)
#define WS_NEED     (BR_OFF + 128)                // ~34.1 MB (proven available in r2+)

#if __has_builtin(__builtin_amdgcn_exp2f)
#define EXP2F(x) __builtin_amdgcn_exp2f(x)
#else
#define EXP2F(x) exp2f(x)
#endif
#define RCPF(x) __builtin_amdgcn_rcpf(x)

__device__ __forceinline__ float tanh_pm(float xx) {
  return 1.0f - 2.0f * RCPF(1.0f + EXP2F(PM * xx));
}

#define AGT __HIP_MEMORY_SCOPE_AGENT
__device__ __forceinline__ float ld_cg(const float* p) {
  return __hip_atomic_load(p, __ATOMIC_RELAXED, AGT);
}
__device__ __forceinline__ void st_cg(float* p, float v) {
  __hip_atomic_store(p, v, __ATOMIC_RELAXED, AGT);
}

// r3/r9-proven rendezvous: drain stores (barrier => vmcnt(0)) then RELEASE RMW.
__device__ __forceinline__ void post1(int* slot) {
  __syncthreads();
  if (threadIdx.x == 0)
    __hip_atomic_fetch_add(slot, 1, __ATOMIC_RELEASE, AGT);
}
__device__ __forceinline__ void wait4(int* base, int val, int* broken) {
  if (threadIdx.x < 4) {
    const int* f = base + threadIdx.x * 32;
    long it = 0;
    while (__hip_atomic_load(f, __ATOMIC_RELAXED, AGT) < val) {
      __builtin_amdgcn_s_sleep(1);
      if (__hip_atomic_load(broken, __ATOMIC_RELAXED, AGT)) break;
      if (++it > 20000000) {
        __hip_atomic_store(broken, 1, __ATOMIC_RELAXED, AGT);
        break;
      }
    }
  }
  __syncthreads();
}

// fp16-packed persistent gemv: 64 half2 = 128 columns per thread (2 threads/row).
#define GEMV128(accum, W, SRC)                                        \
  _Pragma("unroll")                                                   \
  for (int k = 0; k < 64; ++k) {                                      \
    const float2 w2 = __half22float2(W[k]);                           \
    accum = fmaf(w2.x, SRC[cp * 128 + 2 * k], accum);                 \
    accum = fmaf(w2.y, SRC[cp * 128 + 2 * k + 1], accum);             \
  }

// ---------- kernel 1: Ux = x @ U_w^T + U_b, written INTO out ----------
extern "C" __global__ void __launch_bounds__(1024)
ux_gemm(const float* __restrict__ x, const float* __restrict__ U_w,
        const float* __restrict__ U_b, float* __restrict__ out)
{
  const int row0 = blockIdx.x * 16;      // 16 rows of [T*B, H]
  const int tid  = threadIdx.x;
  const int h    = tid & 255;
  const int sub  = tid >> 8;             // 0..3
  __shared__ float sx[16][HH];
  for (int i = tid; i < 16 * HH; i += 1024)
    sx[i >> 8][i & 255] = x[(size_t)row0 * HH + i];
  __syncthreads();
  const float* wrow = U_w + h * HH;
  const float bias = U_b[h];
  float a0 = bias, a1 = bias, a2 = bias, a3 = bias;
  for (int i = 0; i < HH; i += 4) {
    const float4 w4 = *(const float4*)(wrow + i);
#define STEPR(acc, r)  acc = fmaf(w4.x, sx[r][i], acc);   acc = fmaf(w4.y, sx[r][i+1], acc); \
                       acc = fmaf(w4.z, sx[r][i+2], acc); acc = fmaf(w4.w, sx[r][i+3], acc);
    STEPR(a0, sub)  STEPR(a1, 4 + sub)  STEPR(a2, 8 + sub)  STEPR(a3, 12 + sub)
#undef STEPR
  }
  out[(size_t)(row0 + sub)      * HH + h] = a0;
  out[(size_t)(row0 + 4 + sub)  * HH + h] = a1;
  out[(size_t)(row0 + 8 + sub)  * HH + h] = a2;
  out[(size_t)(row0 + 12 + sub) * HH + h] = a3;
}

// ---------- kernel 2: persistent scan ----------
extern "C" __global__ void __launch_bounds__(NTH, 2)
memrnn_scan(const float* __restrict__ V_w, const float* __restrict__ Ua_w,
            const float* __restrict__ Va_w, const float* __restrict__ vvec,
            float* __restrict__ out, char* __restrict__ wsb)
{
  const int blk = blockIdx.x;
  const int b   = blk & 63;       // batch element
  const int s   = blk >> 6;       // time-slice: owns t2 == s (mod 4)
  const int tid = threadIdx.x;
  const int rr  = tid >> 1;       // gemv row 0..255 (2 threads/row)
  const int cp  = tid & 1;        // col half (128 cols each)
  const int sid = tid >> 6;       // num-pass stripe 0..7
  const int qq  = tid & 63;       // num-pass h-quad 0..63

  __half* mem16 = (__half*)wsb + (size_t)blk * RMAX * HH;   // private fp16 h rows (own t2)
  float*  npart = (float*)(wsb + NP_OFF);
  int* flags  = (int*)(wsb + FL_OFF) + b * 4 * 32;
  int* broken = (int*)(wsb + BR_OFF);

  // ---- full-H weights in registers: 3 x 64 half2 (128 cols each) ----
  __half2 wV[64], wVa[64], wUa[64];
#pragma unroll
  for (int k = 0; k < 64; ++k) {
    const int off = rr * HH + cp * 128 + 2 * k;
    wV [k] = __float22half2_rn(*(const float2*)(V_w  + off));
    wVa[k] = __float22half2_rn(*(const float2*)(Va_w + off));
    wUa[k] = __float22half2_rn(*(const float2*)(Ua_w + off));
  }

  __shared__ __half s_uam[RMAX * HH];   // 128KB: PM*uam rows (own t2), XOR-swizzled
  __shared__ float  s_v[HH], s_a[HH], s_ux[HH], s_st[HH], s_h[HH];
  __shared__ float  s_w[RMAX];          // softmax weights for own t2
  __shared__ float  s_np[8][HH];
  __shared__ float  s_npd[8];

  // ================= prologue (t = 0): st0 = Ux[0] (read from out) =================
  if (tid < HH) {
    s_ux[tid] = out[(size_t)b * HH + tid];   // ux_gemm output (kernel-boundary ordered)
    s_v[tid]  = vvec[tid];
  }
  __syncthreads();
  float Vs = 0.f;
#pragma unroll 8
  for (int k = 0; k < HH; ++k) Vs += s_v[k];
  float h0sav = 0.f;
  if (tid < HH) {
    const float st0 = s_ux[tid];
    s_st[tid] = st0;
    h0sav = tanh_pm(st0);                 // V(hidden)=0 at t=0
    s_h[tid] = h0sav;
  }
  __syncthreads();
  if (s == 0) {                           // owner of t2=0
    float au = 0.f;
    GEMV128(au, wUa, s_h);
    au += __shfl_xor(au, 1);
    if (cp == 0)
      *(__half*)((char*)s_uam + ((rr * 2) ^ 0)) = __float2half(PM * au);  // row0
    if (tid < HH) mem16[tid] = __float2half(h0sav);
    // out[0] write deferred to G(t=1): all blocks must read out[0]=Ux[0] first
  }

  // ================= main loop =================
  for (int t = 1; t < TT; ++t) {
    __syncthreads();                   // prev-step I writes (LDS/global) visible
    const int cnt = (t - s + 3) >> 2;  // own t2 rows with t2 < t
    const int par = t & 1;             // npart parity buffer

    // -- A: stage Ux[t] from out (safe: owner's I(t) is behind the rendezvous);
    //       a = PM*(Va*st) (redundant full gemv) --
    if (tid < HH) s_ux[tid] = out[((size_t)t * BB + b) * HH + tid];
    {
      float aa = 0.f;
      GEMV128(aa, wVa, s_st);
      aa += __shfl_xor(aa, 1);
      if (cp == 0) s_a[rr] = PM * aa;
    }
    __syncthreads();

    // -- B: e for own t2 (LDS-only, one pair of threads per row) --
    if (rr < cnt) {
      float p2 = 0.f;
#pragma unroll
      for (int m = 0; m < 16; ++m) {
        const uint4 raw = *(const uint4*)((const char*)s_uam + rr * 512 +
                                          (((cp << 8) | (m << 4)) ^ ((rr & 7) << 4)));
        const __half2* hp = (const __half2*)&raw;
#pragma unroll
        for (int e = 0; e < 4; ++e) {
          const float2 f = __half22float2(hp[e]);
          const int h = cp * 128 + m * 8 + e * 2;
          p2 = fmaf(s_v[h],     RCPF(1.f + EXP2F(s_a[h]     + f.x)), p2);
          p2 = fmaf(s_v[h + 1], RCPF(1.f + EXP2F(s_a[h + 1] + f.y)), p2);
        }
      }
      p2 += __shfl_xor(p2, 1);
      if (cp == 0) s_w[rr] = EXP2F(L2E * (Vs - 2.f * p2));   // exp(e), |e|<=~13
    }
    __syncthreads();

    // -- C: partial num/den over own rows (mem16 private, coalesced 8B loads) --
    {
      float n0 = 0.f, n1 = 0.f, n2 = 0.f, n3 = 0.f, dd = 0.f;
      for (int g = sid; g < cnt; g += 8) {
        const float w = s_w[g];
        const uint2 rawm = *(const uint2*)(mem16 + (size_t)g * HH + qq * 4);
        const float2 f0 = __half22float2(*(const __half2*)&rawm.x);
        const float2 f1 = __half22float2(*(const __half2*)&rawm.y);
        n0 = fmaf(w, f0.x, n0); n1 = fmaf(w, f0.y, n1);
        n2 = fmaf(w, f1.x, n2); n3 = fmaf(w, f1.y, n3);
        dd += w;
      }
      s_np[sid][qq * 4 + 0] = n0; s_np[sid][qq * 4 + 1] = n1;
      s_np[sid][qq * 4 + 2] = n2; s_np[sid][qq * 4 + 3] = n3;
      if (qq == 0) s_npd[sid] = dd;
    }
    __syncthreads();

    // -- D: publish record into parity buffer; post flag --
    {
      float* rec = npart + (((size_t)b * 4 + s) * 2 + par) * NP_STRIDE;
      if (tid < HH) {
        float nm = 0.f;
#pragma unroll
        for (int i = 0; i < 8; ++i) nm += s_np[i][tid];
        st_cg(rec + tid, nm);
      } else if (tid == HH) {
        float dn = 0.f;
#pragma unroll
        for (int i = 0; i < 8; ++i) dn += s_npd[i];
        st_cg(rec + 256, dn);
      }
    }
    post1(flags + s * 32);

    // -- F: single rendezvous --
    wait4(flags, t, broken);

    // -- G: combine (parity buffer) -> ct -> st_new (redundant, identical) --
    if (tid < HH) {
      const float* np0 = npart + ((size_t)b * 8 + par) * NP_STRIDE;
      const float nm = ld_cg(np0 + tid) + ld_cg(np0 + 2 * NP_STRIDE + tid) +
                       ld_cg(np0 + 4 * NP_STRIDE + tid) + ld_cg(np0 + 6 * NP_STRIDE + tid);
      const float dn = ld_cg(np0 + 256) + ld_cg(np0 + 2 * NP_STRIDE + 256) +
                       ld_cg(np0 + 4 * NP_STRIDE + 256) + ld_cg(np0 + 6 * NP_STRIDE + 256);
      s_st[tid] = s_h[tid] + nm * RCPF(dn);       // last_h + ct
    }
    if (t == 1 && s == 0 && tid < HH)
      out[(size_t)b * HH + tid] = h0sav;          // deferred mem[0] write (WAR-safe now)
    __syncthreads();

    // -- H: h = tanh(V*st_new + Ux[t]) (bias folded into Ux) --
    {
      float ah = 0.f;
      GEMV128(ah, wV, s_st);
      ah += __shfl_xor(ah, 1);
      if (cp == 0) s_h[rr] = tanh_pm(ah + s_ux[rr]);
    }
    __syncthreads();

    // -- I: owner of t2=t stores uam row (LDS), mem16 row, out row --
    if (s == (t & 3)) {
      float au = 0.f;
      GEMV128(au, wUa, s_h);
      au += __shfl_xor(au, 1);
      const int row = t >> 2;
      if (cp == 0)
        *(__half*)((char*)s_uam + row * 512 + ((rr * 2) ^ ((row & 7) << 4))) =
            __float2half(PM * au);
      if (tid < HH) {
        mem16[(size_t)row * HH + tid] = __float2half(s_h[tid]);
        out[((size_t)t * BB + b) * HH + tid] = s_h[tid];
      }
    }
  }

  if (tid == 0 && __hip_atomic_load(broken, __ATOMIC_RELAXED, AGT))
    st_cg(&out[0], 1.0e6f);   // deadlock signature
}

__global__ void ws_sentinel(float* out) { out[0] = 2.0e6f; }

extern "C" void kernel_launch(void* const* d_in, const int* in_sizes, int n_in,
                              void* d_out, int out_size, void* d_ws, size_t ws_size,
                              hipStream_t stream) {
  const float* x    = (const float*)d_in[0];
  const float* U_w  = (const float*)d_in[1];
  const float* U_b  = (const float*)d_in[2];
  const float* V_w  = (const float*)d_in[3];
  const float* Ua_w = (const float*)d_in[4];
  const float* Va_w = (const float*)d_in[5];
  const float* v    = (const float*)d_in[6];
  float* out = (float*)d_out;

  if (ws_size < WS_NEED) {            // diagnosable failure signature (absmax ~2e6)
    ws_sentinel<<<1, 1, 0, stream>>>(out);
    return;
  }
  hipMemsetAsync((char*)d_ws + FL_OFF, 0, (size_t)(WS_NEED - FL_OFF), stream);
  ux_gemm<<<dim3(TT * BB / 16), dim3(1024), 0, stream>>>(x, U_w, U_b, out);
  memrnn_scan<<<dim3(BB * 4), dim3(NTH), 0, stream>>>(
      V_w, Ua_w, Va_w, v, out, (char*)d_ws);
}

// Round 11
// 31524.261 us; speedup vs baseline: 4.1582x; 2.2251x over previous
//
#include <hip/hip_runtime.h>
#include <hip/hip_fp16.h>

#define TT 1024
#define BB 64
#define HH 256
#define NQ 4
#define SL 64
#define NTH 1024

#define L2E 1.44269504089f
#define PM  2.88539008178f  // 2*log2(e): tanh(x) = 1 - 2/(1+2^(PM*x))

// ---- ws layout ----
#define EP_OFF   0ull                               // ep [B][4][T] f32   (1 MB)
#define STW_OFF  (EP_OFF + 1ull * BB * NQ * TT * 4) // st [B][H] f32
#define MIR_OFF  (STW_OFF + 1ull * BB * HH * 4)     // mir fp16 [256 blk][T][64] (32 MB)
#define AF_OFF   (MIR_OFF + 256ull * TT * SL * 2)
#define BF_OFF   (AF_OFF + 1ull * BB * NQ * 32 * 4)
#define BR_OFF   (BF_OFF + 1ull * BB * NQ * 32 * 4)
#define WS_NEED  (BR_OFF + 128)                     // ~34.7 MB (r2+ proven available)

#if __has_builtin(__builtin_amdgcn_exp2f)
#define EXP2F(x) __builtin_amdgcn_exp2f(x)
#else
#define EXP2F(x) exp2f(x)
#endif
#define RCPF(x) __builtin_amdgcn_rcpf(x)

__device__ __forceinline__ float tanh_pm(float xx) {
  return 1.0f - 2.0f * RCPF(1.0f + EXP2F(PM * xx));
}

#define AGT __HIP_MEMORY_SCOPE_AGENT
__device__ __forceinline__ float ld_cg(const float* p) {
  return __hip_atomic_load(p, __ATOMIC_RELAXED, AGT);
}
__device__ __forceinline__ void st_cg(float* p, float v) {
  __hip_atomic_store(p, v, __ATOMIC_RELAXED, AGT);
}

// r3-proven rendezvous: __syncthreads drains all stores (vmcnt0), then RELEASE RMW.
__device__ __forceinline__ void post1(int* slot) {
  __syncthreads();
  if (threadIdx.x == 0)
    __hip_atomic_fetch_add(slot, 1, __ATOMIC_RELEASE, AGT);
}
__device__ __forceinline__ void wait4(int* base, int val, int* broken) {
  if (threadIdx.x < 4) {
    const int* f = base + threadIdx.x * 32;
    long it = 0;
    while (__hip_atomic_load(f, __ATOMIC_RELAXED, AGT) < val) {
      __builtin_amdgcn_s_sleep(1);
      if (__hip_atomic_load(broken, __ATOMIC_RELAXED, AGT)) break;
      if (++it > 20000000) {
        __hip_atomic_store(broken, 1, __ATOMIC_RELAXED, AGT);
        break;
      }
    }
  }
  __syncthreads();
}

#define RED16(a) { a += __shfl_xor(a, 1); a += __shfl_xor(a, 2); \
                   a += __shfl_xor(a, 4); a += __shfl_xor(a, 8); }

// ---------- kernel 1: Ux = x @ U_w^T + U_b, written INTO out (r10-proven) ----------
extern "C" __global__ void __launch_bounds__(1024)
ux_gemm(const float* __restrict__ x, const float* __restrict__ U_w,
        const float* __restrict__ U_b, float* __restrict__ out)
{
  const int row0 = blockIdx.x * 16;
  const int tid  = threadIdx.x;
  const int h    = tid & 255;
  const int sub  = tid >> 8;
  __shared__ float sx[16][HH];
  for (int i = tid; i < 16 * HH; i += 1024)
    sx[i >> 8][i & 255] = x[(size_t)row0 * HH + i];
  __syncthreads();
  const float* wrow = U_w + h * HH;
  const float bias = U_b[h];
  float a0 = bias, a1 = bias, a2 = bias, a3 = bias;
  for (int i = 0; i < HH; i += 4) {
    const float4 w4 = *(const float4*)(wrow + i);
#define STEPR(acc, r)  acc = fmaf(w4.x, sx[r][i], acc);   acc = fmaf(w4.y, sx[r][i+1], acc); \
                       acc = fmaf(w4.z, sx[r][i+2], acc); acc = fmaf(w4.w, sx[r][i+3], acc);
    STEPR(a0, sub)  STEPR(a1, 4 + sub)  STEPR(a2, 8 + sub)  STEPR(a3, 12 + sub)
#undef STEPR
  }
  out[(size_t)(row0 + sub)      * HH + h] = a0;
  out[(size_t)(row0 + 4 + sub)  * HH + h] = a1;
  out[(size_t)(row0 + 8 + sub)  * HH + h] = a2;
  out[(size_t)(row0 + 12 + sub) * HH + h] = a3;
}

// ---------- kernel 2: persistent scan (r3 structure, 2 rendezvous) ----------
extern "C" __global__ void __launch_bounds__(NTH)
memrnn_scan(const float* __restrict__ V_w, const float* __restrict__ Ua_w,
            const float* __restrict__ Va_w, const float* __restrict__ vvec,
            float* __restrict__ out, char* __restrict__ wsb)
{
  const int blk  = blockIdx.x;
  const int b    = blk & 63;     // batch; group {b, b+64, b+128, b+192}
  const int q    = blk >> 6;     // h-slice (64 h each)
  const int tid  = threadIdx.x;
  const int lane = tid & 63;
  const int wav  = tid >> 6;     // 0..15
  const int r    = tid >> 4;     // slice gemv row 0..63 (16 thr/row)
  const int c    = tid & 15;
  const int gr   = q * SL + r;   // global h row for slice gemvs
  const int r4   = tid >> 2;     // full gemv row 0..255 (4 thr/row)
  const int c4   = tid & 3;

  float*  ep  = (float*)(wsb + EP_OFF);
  float*  stw = (float*)(wsb + STW_OFF);
  __half* mir = (__half*)(wsb + MIR_OFF) + (size_t)blk * TT * SL;  // private fp16 h-slice history
  int* aflag  = (int*)(wsb + AF_OFF) + b * NQ * 32;
  int* bflag  = (int*)(wsb + BF_OFF) + b * NQ * 32;
  int* broken = (int*)(wsb + BR_OFF);

  // persistent weights: Va,Ua slices f32 (16/thr); V full fp16 (32 half2/thr)
  float wVa[16], wUa[16];
#pragma unroll
  for (int j = 0; j < 16; ++j) {
    wVa[j] = Va_w[gr * HH + j * 16 + c];
    wUa[j] = Ua_w[gr * HH + j * 16 + c];
  }
  __half2 wVh[32];
#pragma unroll
  for (int k = 0; k < 32; ++k)
    wVh[k] = __float22half2_rn(*(const float2*)(V_w + r4 * HH + c4 * 64 + 2 * k));

  __shared__ __half s_uam[SL * TT];   // [h_local][t2] PM*uam slice history, 128 KB
  __shared__ float  s_v[SL];          // v own slice
  __shared__ float  s_a[SL];          // PM*(Va*st) own slice
  __shared__ float  s_ux[HH];         // Ux[t] staging
  __shared__ float  s_st[HH];         // full st
  __shared__ float  s_h[HH];          // full h (mem[t-1] at P2-time)
  __shared__ float  s_w[TT];          // softmax weights
  __shared__ float  s_red[16 * SL];
  __shared__ float  s_d[16];

  float* epg = ep + (size_t)(b * NQ + q) * TT;

  // ================= prologue (t=0) =================
  if (tid < HH) s_ux[tid] = out[(size_t)b * HH + tid];   // Ux[0] (ux_gemm, kernel-ordered)
  if (tid < SL) s_v[tid]  = vvec[q * SL + tid];
  __syncthreads();
  if (tid < HH) {
    const float st0 = s_ux[tid];
    s_st[tid] = st0;
    s_h[tid]  = tanh_pm(st0);          // h0 (V(hidden)=0 at t=0)
  }
  __syncthreads();
  float Vs = 0.f;
#pragma unroll 8
  for (int k = 0; k < SL; ++k) Vs += s_v[k];
  {   // uam[0] slice -> LDS row t2=0; mir[0] slice
    float au = 0.f;
#pragma unroll
    for (int j = 0; j < 16; ++j) au = fmaf(wUa[j], s_h[j * 16 + c], au);
    RED16(au);
    if (c == 0) s_uam[r * TT + 0] = __float2half(PM * au);
    if (tid < SL) mir[tid] = __float2half(s_h[q * SL + tid]);
    // out[0] write deferred (all blocks must read Ux[0] first)
  }

  // ================= main loop =================
  for (int t = 1; t < TT; ++t) {
    // -- P1a: stage Ux[t] (safe: pre-alpha-post; owners write out[t] post-beta);
    //         a = PM*(Va_slice * st) --
    if (tid < HH) s_ux[tid] = out[((size_t)t * BB + b) * HH + tid];
    {
      float aa = 0.f;
#pragma unroll
      for (int j = 0; j < 16; ++j) aa = fmaf(wVa[j], s_st[j * 16 + c], aa);
      RED16(aa);
      if (c == 0) s_a[r] = PM * aa;
    }
    __syncthreads();   // also orders prev-step s_uam row write before P1b reads

    // -- P1b: e-partial for own h-slice, all t2 < t (LDS-only; lane = t2) --
    if (tid < t) {
      float p2 = 0.f;
#pragma unroll 8
      for (int hh = 0; hh < SL; ++hh) {
        const float u = __half2float(s_uam[hh * TT + tid]);
        p2 = fmaf(s_v[hh], RCPF(1.f + EXP2F(s_a[hh] + u)), p2);
      }
      st_cg(&epg[tid], Vs - 2.f * p2);
    }
    post1(aflag + q * 32);                         // alpha -> t
    wait4(aflag, t, broken);

    // -- P2a: combine e-partials -> weights (exp) --
    if (tid < t) {
      const float* e0 = ep + (size_t)b * NQ * TT + tid;
      s_w[tid] = EXP2F(L2E * (ld_cg(e0) + ld_cg(e0 + TT) +
                              ld_cg(e0 + 2 * TT) + ld_cg(e0 + 3 * TT)));
    }
    __syncthreads();

    // -- P2b: num/den over own h-slice from private mir (r3's L2-proven pattern) --
    {
      float num = 0.f, den = 0.f;
      const __half* mq = mir + lane;
#pragma unroll 4
      for (int t2 = wav; t2 < t; t2 += 16) {
        const float w = s_w[t2];
        den += w;
        num = fmaf(w, __half2float(mq[(size_t)t2 * SL]), num);
      }
      s_red[wav * SL + lane] = num;
      if (lane == 0) s_d[wav] = den;
    }
    __syncthreads();
    if (wav == 0) {
      float nt = 0.f, dt = 0.f;
#pragma unroll
      for (int w2 = 0; w2 < 16; ++w2) { nt += s_red[w2 * SL + lane]; dt += s_d[w2]; }
      const float stn = s_h[q * SL + lane] + nt * RCPF(dt);   // last_h + ct
      st_cg(&stw[b * HH + q * SL + lane], stn);
    }
    post1(bflag + q * 32);                         // beta -> t
    wait4(bflag, t, broken);

    // -- P3: full st; deferred out[0] --
    if (tid < HH) s_st[tid] = ld_cg(&stw[b * HH + tid]);
    if (t == 1 && tid < SL) out[(size_t)b * HH + q * SL + tid] = s_h[q * SL + tid];
    __syncthreads();

    // -- P3b: h = tanh(V*st + Ux[t]) full, redundant (fp16 V regs, 4 thr/row) --
    {
      float ah = 0.f;
#pragma unroll
      for (int k = 0; k < 32; ++k) {
        const float2 w2 = __half22float2(wVh[k]);
        ah = fmaf(w2.x, s_st[c4 * 64 + 2 * k], ah);
        ah = fmaf(w2.y, s_st[c4 * 64 + 2 * k + 1], ah);
      }
      ah += __shfl_xor(ah, 1); ah += __shfl_xor(ah, 2);
      if (c4 == 0) s_h[r4] = tanh_pm(ah + s_ux[r4]);
    }
    __syncthreads();

    // -- P4: uam slice row t -> LDS; mir/out slice writes (all local) --
    {
      float au = 0.f;
#pragma unroll
      for (int j = 0; j < 16; ++j) au = fmaf(wUa[j], s_h[j * 16 + c], au);
      RED16(au);
      if (c == 0) s_uam[r * TT + t] = __float2half(PM * au);
      if (tid < SL) {
        mir[(size_t)t * SL + tid] = __float2half(s_h[q * SL + tid]);
        out[((size_t)t * BB + b) * HH + q * SL + tid] = s_h[q * SL + tid];
      }
    }
    // no trailing sync: next P1a writes s_ux/s_a only; P1's sync orders s_uam row t
  }

  if (tid == 0 && __hip_atomic_load(broken, __ATOMIC_RELAXED, AGT))
    st_cg(&out[0], 1.0e6f);   // deadlock signature
}

__global__ void ws_sentinel(float* out) { out[0] = 2.0e6f; }

extern "C" void kernel_launch(void* const* d_in, const int* in_sizes, int n_in,
                              void* d_out, int out_size, void* d_ws, size_t ws_size,
                              hipStream_t stream) {
  const float* x    = (const float*)d_in[0];
  const float* U_w  = (const float*)d_in[1];
  const float* U_b  = (const float*)d_in[2];
  const float* V_w  = (const float*)d_in[3];
  const float* Ua_w = (const float*)d_in[4];
  const float* Va_w = (const float*)d_in[5];
  const float* v    = (const float*)d_in[6];
  float* out = (float*)d_out;

  if (ws_size < WS_NEED) {            // diagnosable failure signature (absmax ~2e6)
    ws_sentinel<<<1, 1, 0, stream>>>(out);
    return;
  }
  hipMemsetAsync((char*)d_ws + AF_OFF, 0, (size_t)(WS_NEED - AF_OFF), stream);
  ux_gemm<<<dim3(TT * BB / 16), dim3(1024), 0, stream>>>(x, U_w, U_b, out);
  memrnn_scan<<<dim3(BB * NQ), dim3(NTH), 0, stream>>>(
      V_w, Ua_w, Va_w, v, out, (char*)d_ws);
}